// Round 8
// baseline (134.752 us; speedup 1.0000x reference)
//
#include <hip/hip_runtime.h>

// Problem constants (match reference)
#define VOCABN 100
#define EMBEDN 16
#define STATEN 7
#define OUTN   10
#define BATCHN 4096
#define SEQT   512
#define L2E 1.44269504088896340736f

typedef float v2f __attribute__((ext_vector_type(2)));

__device__ __forceinline__ float fexp2(float x){ float r; asm("v_exp_f32 %0, %1":"=v"(r):"v"(x)); return r; }
__device__ __forceinline__ float frcp (float x){ float r; asm("v_rcp_f32 %0, %1":"=v"(r):"v"(x)); return r; }

// DPP helpers. row_ror:n = 0x120+n (16-lane ring; even n preserves parity).
template<int C> __device__ __forceinline__ int dppi(int x){
  return __builtin_amdgcn_update_dpp(0, x, C, 0xF, 0xF, true);
}
template<int C> __device__ __forceinline__ float dppf(float x){
  return __int_as_float(__builtin_amdgcn_update_dpp(0, __float_as_int(x), C, 0xF, 0xF, true));
}

// ---------------------------------------------------------------------------
// Pade(7,6) tanh (continued-fraction truncation, exact coefficients):
// tanh(t) ~ t(u^3+378u^2+17325u+135135)/(28u^3+3150u^2+62370u+135135), u=t^2.
// Clamp +-4.5: in-range err <=5e-5, saturated err <=2.04e-4, never NaN/Inf.
// One v_rcp on the path instead of exp2->add->rcp (two serial trans).
// ---------------------------------------------------------------------------
__device__ __forceinline__ v2f ptanh2(v2f z){
  v2f t = __builtin_elementwise_min(
            __builtin_elementwise_max(z, (v2f){-4.5f,-4.5f}), (v2f){4.5f,4.5f});
  v2f u = t*t;
  v2f n = __builtin_elementwise_fma(
            __builtin_elementwise_fma(u + (v2f){378.0f,378.0f}, u,
                                      (v2f){17325.0f,17325.0f}), u,
            (v2f){135135.0f,135135.0f});
  v2f d = __builtin_elementwise_fma(
            __builtin_elementwise_fma(
              __builtin_elementwise_fma(u,(v2f){28.0f,28.0f},(v2f){3150.0f,3150.0f}),
              u, (v2f){62370.0f,62370.0f}), u,
            (v2f){135135.0f,135135.0f});
  v2f nt = n*t;
  return (v2f){ nt.x*frcp(d.x), nt.y*frcp(d.y) };
}
__device__ __forceinline__ float ptanh1(float z){
  float t = fminf(fmaxf(z,-4.5f),4.5f);
  float u = t*t;
  float n = __builtin_fmaf(__builtin_fmaf(u+378.0f,u,17325.0f),u,135135.0f);
  float d = __builtin_fmaf(__builtin_fmaf(__builtin_fmaf(u,28.0f,3150.0f),u,62370.0f),u,135135.0f);
  return (n*t)*frcp(d);
}

// ---------------------------------------------------------------------------
// Kernel A: embW[v][slot][gate] = (b + x@W) per gate col, pre-scaled:
// sigmoid gates (i,f,o) x0.5 (sigma(z)=0.5+0.5*tanh(z/2) prefold); g x1.
// slot = (s+v)&7 bank rotation; pad state s=7 -> zeros. TRUE domain (no L2E).
// ---------------------------------------------------------------------------
__global__ void embw_kernel(const float* __restrict__ emb, const float* __restrict__ W,
                            const float* __restrict__ b, float* __restrict__ embw){
  int v = blockIdx.x, j = threadIdx.x;          // j 0..31
  int s = j >> 2, gate = j & 3;
  float val = 0.0f;
  if (s < STATEN) {
    int col = gate*STATEN + s;
    val = b[col];
    #pragma unroll
    for (int e = 0; e < EMBEDN; ++e) val = fmaf(emb[v*EMBEDN+e], W[e*28+col], val);
    val *= (gate == 2) ? 1.0f : 0.5f;
  }
  embw[v*32 + ((s+v)&7)*4 + gate] = val;
}

// ---------------------------------------------------------------------------
// Kernel B: whole-state lanes, Pade gates — shortest serial path.
// 64 thr = 1 wave = 4 DPP rows x 2 parity-interleaved chains = 8 chains/block.
// Lane (row, parity q, s=pos>>1) owns ALL FOUR gates of state s for chain
// row*2+q: no mid-gate cross-lane exchanges, cell update fully lane-local.
// Per-step path: 7-DPP h-broadcast -> packed z (4 cols, 2x v2f) -> packed
// Pade tanh (1 rcp) -> i,f,o=0.5+0.5t; g=t -> c fma -> scalar Pade tanh(c)
// (1 rcp) -> h = o*tanhc -> next broadcast.  ~P = 150 + 2*rcp-latency.
// Flush: lane s handles its chain's timestep s of each octet, full 10-way
// softmax per lane (no cross-lane), staged branch-free across the next octet.
// 512 blocks; latency-bound per wave, idle SIMDs don't matter.
// ---------------------------------------------------------------------------
__global__ void __launch_bounds__(64,1)
lstm_kernel(const int* __restrict__ tokens, const float* __restrict__ embw,
            const float* __restrict__ U, const float* __restrict__ Wd,
            const float* __restrict__ bdv, float* __restrict__ out){
  __shared__ float embW_s[VOCABN*32];   // 12.8 KB
  __shared__ int   tok_s[8*520];        // 16.6 KB (+pads for over-read)

  const int tid = threadIdx.x;
  const int b0 = blockIdx.x*8;

  for (int i=tid;i<VOCABN*8;i+=64) ((float4*)embW_s)[i]=((const float4*)embw)[i];
  for (int i=tid;i<8*128;i+=64){ int r=i>>7,c4=i&127;
    int4 v=((const int4*)(tokens+(size_t)(b0+r)*SEQT))[c4];
    *((int4*)&tok_s[r*520+c4*4])=v; }
  if (tid<8){ tok_s[tid*520+512]=0; tok_s[tid*520+513]=0; tok_s[tid*520+514]=0; }
  __syncthreads();

  const int pos=tid&15, row=tid>>4, s=pos>>1, q=pos&1;
  const int ch = row*2 + q;                 // chain in block, 0..7

  // sigma discovery: push own state id through the exact broadcast net
  int sg[8];
  sg[0]=s;
  sg[1]=dppi<0x122>(s); sg[2]=dppi<0x124>(s); sg[3]=dppi<0x126>(s);
  sg[4]=dppi<0x128>(s); sg[5]=dppi<0x12A>(s); sg[6]=dppi<0x12C>(s); sg[7]=dppi<0x12E>(s);

  // recurrent weights: per h-term k, packed {i,f} and {g,o} cols of own state.
  // sigmoid cols (i,f,o) prefolded x0.5; g x1. Pre-permuted by sigma.
  v2f Uif[8], Ugo[8];
  #pragma unroll
  for (int k=0;k<8;++k){
    int sk=sg[k]; bool vld=(sk<STATEN)&&(s<STATEN);
    Uif[k].x = vld ? U[sk*28 + 0*7 + s]*0.5f : 0.0f;
    Uif[k].y = vld ? U[sk*28 + 1*7 + s]*0.5f : 0.0f;
    Ugo[k].x = vld ? U[sk*28 + 2*7 + s]      : 0.0f;
    Ugo[k].y = vld ? U[sk*28 + 3*7 + s]*0.5f : 0.0f;
  }
  // dense weights, pre-permuted by sigma, L2E-scaled (softmax uses fexp2)
  float Wdc[8][10], bdr[10];
  #pragma unroll
  for (int k=0;k<8;++k){ int sk=sg[k];
    #pragma unroll
    for (int o=0;o<OUTN;++o) Wdc[k][o] = (sk<STATEN)? Wd[sk*10+o]*L2E : 0.0f; }
  #pragma unroll
  for (int o=0;o<OUTN;++o) bdr[o]=bdv[o]*L2E;

  const int* trow=&tok_s[ch*520];
  float* outp = out + ((size_t)(b0+ch)*SEQT + s)*OUTN;

  float hh[8], hc[8], lg[10], ee[10];
  #pragma unroll
  for (int k=0;k<8;++k){ hh[k]=0.0f; hc[k]=0.0f; }
  #pragma unroll
  for (int o=0;o<OUTN;++o){ lg[o]=0.0f; ee[o]=0.0f; }
  float mx=0.0f, rs=0.0f;

  // prefetch queues: embW depth-2, token depth-3
  int tk2 = trow[2];
  float4 pf0 = *(const float4*)&embW_s[trow[0]*32 + (((s+trow[0])&7)<<2)];
  float4 pf1 = *(const float4*)&embW_s[trow[1]*32 + (((s+trow[1])&7)<<2)];
  float Cc=0.0f, h=0.0f;

  for (int t8=0;t8<SEQT;t8+=8){
    #pragma unroll
    for (int u=0;u<8;++u){
      float4 pf2 = *(const float4*)&embW_s[tk2*32 + (((s+tk2)&7)<<2)];
      int tk3 = trow[t8+u+3];

      // broadcast h_{t-1} across the 8-lane chain (7 parity-preserving DPPs)
      float r0=h;
      float r1=dppf<0x122>(h), r2=dppf<0x124>(h), r3=dppf<0x126>(h);
      float r4=dppf<0x128>(h), r5=dppf<0x12A>(h), r6=dppf<0x12C>(h), r7=dppf<0x12E>(h);

      // lane of state s captures h-vector of timestep t-1 when u==s+1 (mod 8)
      bool cap = (s==((u+7)&7));
      hh[0]=cap?r0:hh[0]; hh[1]=cap?r1:hh[1]; hh[2]=cap?r2:hh[2]; hh[3]=cap?r3:hh[3];
      hh[4]=cap?r4:hh[4]; hh[5]=cap?r5:hh[5]; hh[6]=cap?r6:hh[6]; hh[7]=cap?r7:hh[7];

      // ---- staged flush of the PREVIOUS octet (off the serial path) ----
      if (u==0){ hc[0]=hh[0];hc[1]=hh[1];hc[2]=hh[2];hc[3]=hh[3];
                 hc[4]=hh[4];hc[5]=hh[5];hc[6]=hh[6];hc[7]=hh[7]; }
      if (u==1){
        #pragma unroll
        for (int o=0;o<3;++o){ float a=bdr[o];
          #pragma unroll
          for (int k=0;k<8;++k) a=__builtin_fmaf(hc[k],Wdc[k][o],a);
          lg[o]=a; } }
      if (u==2){
        #pragma unroll
        for (int o=3;o<6;++o){ float a=bdr[o];
          #pragma unroll
          for (int k=0;k<8;++k) a=__builtin_fmaf(hc[k],Wdc[k][o],a);
          lg[o]=a; } }
      if (u==3){
        #pragma unroll
        for (int o=6;o<OUTN;++o){ float a=bdr[o];
          #pragma unroll
          for (int k=0;k<8;++k) a=__builtin_fmaf(hc[k],Wdc[k][o],a);
          lg[o]=a; } }
      if (u==4){
        float m0=fmaxf(fmaxf(lg[0],lg[1]),fmaxf(lg[2],lg[3]));
        float m1=fmaxf(fmaxf(lg[4],lg[5]),fmaxf(lg[6],lg[7]));
        mx=fmaxf(fmaxf(m0,m1),fmaxf(lg[8],lg[9])); }
      if (u==5){
        ee[0]=fexp2(lg[0]-mx); ee[1]=fexp2(lg[1]-mx); ee[2]=fexp2(lg[2]-mx);
        ee[3]=fexp2(lg[3]-mx); ee[4]=fexp2(lg[4]-mx); ee[5]=fexp2(lg[5]-mx);
        ee[6]=fexp2(lg[6]-mx); ee[7]=fexp2(lg[7]-mx); ee[8]=fexp2(lg[8]-mx);
        ee[9]=fexp2(lg[9]-mx); }
      if (u==6){
        float sm=(((ee[0]+ee[1])+(ee[2]+ee[3]))+((ee[4]+ee[5])+(ee[6]+ee[7])))+(ee[8]+ee[9]);
        rs=frcp(sm); }
      if (u==7){
        if (t8>0){
          float2* op=(float2*)outp;
          op[0]=make_float2(ee[0]*rs,ee[1]*rs);
          op[1]=make_float2(ee[2]*rs,ee[3]*rs);
          op[2]=make_float2(ee[4]*rs,ee[5]*rs);
          op[3]=make_float2(ee[6]*rs,ee[7]*rs);
          op[4]=make_float2(ee[8]*rs,ee[9]*rs);
          outp += 8*OUTN;
        } }

      // ---- z (4 gate cols as 2x v2f), tree-shaped packed FMA ----
      v2f zif = {pf0.x, pf0.y}, zgo = {pf0.z, pf0.w};
      v2f a01 = __builtin_elementwise_fma((v2f){r1,r1},Uif[1],
                __builtin_elementwise_fma((v2f){r0,r0},Uif[0],zif));
      v2f a23 = __builtin_elementwise_fma((v2f){r3,r3},Uif[3],(v2f){r2,r2}*Uif[2]);
      v2f a45 = __builtin_elementwise_fma((v2f){r5,r5},Uif[5],(v2f){r4,r4}*Uif[4]);
      v2f a67 = __builtin_elementwise_fma((v2f){r7,r7},Uif[7],(v2f){r6,r6}*Uif[6]);
      zif = (a01+a23)+(a45+a67);
      v2f b01 = __builtin_elementwise_fma((v2f){r1,r1},Ugo[1],
                __builtin_elementwise_fma((v2f){r0,r0},Ugo[0],zgo));
      v2f b23 = __builtin_elementwise_fma((v2f){r3,r3},Ugo[3],(v2f){r2,r2}*Ugo[2]);
      v2f b45 = __builtin_elementwise_fma((v2f){r5,r5},Ugo[5],(v2f){r4,r4}*Ugo[4]);
      v2f b67 = __builtin_elementwise_fma((v2f){r7,r7},Ugo[7],(v2f){r6,r6}*Ugo[6]);
      zgo = (b01+b23)+(b45+b67);

      // ---- gates via Pade tanh (one rcp stage for all four, lane-local) ----
      v2f tif = ptanh2(zif);          // tanh(zi/2), tanh(zf/2)
      v2f tgo = ptanh2(zgo);          // tanh(zg),   tanh(zo/2)
      float gi = __builtin_fmaf(tif.x,0.5f,0.5f);
      float gf = __builtin_fmaf(tif.y,0.5f,0.5f);
      float gg = tgo.x;
      float go = __builtin_fmaf(tgo.y,0.5f,0.5f);
      Cc = __builtin_fmaf(gf,Cc,gi*gg);
      h  = go * ptanh1(Cc);           // second (and last) rcp stage

      pf0=pf1; pf1=pf2; tk2=tk3;
    }
  }

  // ---- epilogue: capture h_511 (slot 7), flush final octet (ts 504..511) ----
  {
    float r0=h;
    float r1=dppf<0x122>(h), r2=dppf<0x124>(h), r3=dppf<0x126>(h);
    float r4=dppf<0x128>(h), r5=dppf<0x12A>(h), r6=dppf<0x12C>(h), r7=dppf<0x12E>(h);
    bool cap = (s==7);
    hh[0]=cap?r0:hh[0]; hh[1]=cap?r1:hh[1]; hh[2]=cap?r2:hh[2]; hh[3]=cap?r3:hh[3];
    hh[4]=cap?r4:hh[4]; hh[5]=cap?r5:hh[5]; hh[6]=cap?r6:hh[6]; hh[7]=cap?r7:hh[7];
    float a[10];
    #pragma unroll
    for (int o=0;o<OUTN;++o){ a[o]=bdr[o];
      #pragma unroll
      for (int k=0;k<8;++k) a[o]=__builtin_fmaf(hh[k],Wdc[k][o],a[o]); }
    float m0=fmaxf(fmaxf(a[0],a[1]),fmaxf(a[2],a[3]));
    float m1=fmaxf(fmaxf(a[4],a[5]),fmaxf(a[6],a[7]));
    float m=fmaxf(fmaxf(m0,m1),fmaxf(a[8],a[9]));
    float e[10], sm=0.0f;
    #pragma unroll
    for (int o=0;o<OUTN;++o){ e[o]=fexp2(a[o]-m); sm+=e[o]; }
    float r=frcp(sm);
    float2* op=(float2*)outp;
    op[0]=make_float2(e[0]*r,e[1]*r);
    op[1]=make_float2(e[2]*r,e[3]*r);
    op[2]=make_float2(e[4]*r,e[5]*r);
    op[3]=make_float2(e[6]*r,e[7]*r);
    op[4]=make_float2(e[8]*r,e[9]*r);
  }
}

// ---------------------------------------------------------------------------
// inputs: 0 tokens 1 emb 2 W 3 U 4 b 5 Wd 6 bd ; out f32 B*T*10.
// d_ws: 12800 B for the pre-scaled embW table (rewritten every call).
// ---------------------------------------------------------------------------
extern "C" void kernel_launch(void* const* d_in, const int* in_sizes, int n_in,
                              void* d_out, int out_size, void* d_ws, size_t ws_size,
                              hipStream_t stream) {
  const int*   tokens = (const int*)d_in[0];
  const float* emb    = (const float*)d_in[1];
  const float* W      = (const float*)d_in[2];
  const float* U      = (const float*)d_in[3];
  const float* b      = (const float*)d_in[4];
  const float* Wd     = (const float*)d_in[5];
  const float* bd     = (const float*)d_in[6];
  float* outp = (float*)d_out;
  float* embw = (float*)d_ws;

  embw_kernel<<<dim3(VOCABN), dim3(32), 0, stream>>>(emb, W, b, embw);
  lstm_kernel<<<dim3(BATCHN/8), dim3(64), 0, stream>>>(tokens, embw, U, Wd, bd, outp);
}